// Round 8
// baseline (212.242 us; speedup 1.0000x reference)
//
#include <hip/hip_runtime.h>

typedef unsigned short u16;
typedef unsigned int u32;
typedef unsigned long long u64;
typedef long long i64;
typedef __bf16 bf16x8 __attribute__((ext_vector_type(8)));
typedef u16 u16x8 __attribute__((ext_vector_type(8)));
typedef float f32x4 __attribute__((ext_vector_type(4)));
typedef float f32x16 __attribute__((ext_vector_type(16)));

#define DEV __device__ __forceinline__

// problem constants (fixed by harness)
constexpr int BB = 2, DD = 512, NN = 2048, HH = 8, DKc = 64, D2 = 1024;

// Q pre-scale: 1/sqrt(64) * log2(e)  (folded into Q so softmax uses native exp2)
constexpr float QSC = 0.125f * 1.44269504088896340736f;

// workspace byte offsets (16B aligned); NO aliasing
constexpr i64 MB = 1048576;
constexpr i64 OFF_CAT = 0;          // bf16 [B][N][D2]; [0:512)=attn (flash tail), [512:1024)=iq^T
constexpr i64 OFF_XKT = 8 * MB;     // bf16 [B][N][D] key_t^T
constexpr i64 OFF_XVT = 12 * MB;    // bf16 [B][N][D] value^T
constexpr i64 OFF_QH  = 16 * MB;    // bf16 [B][H][N][DK] (Q pre-scaled by QSC)
constexpr i64 OFF_KH  = 20 * MB;    // bf16 [B][H][N][DK]
constexpr i64 OFF_VT  = 24 * MB;    // bf16 [B][H][DK][N]  (natural m)
constexpr i64 OFF_HT  = 28 * MB;    // bf16 [B][N][D2]
constexpr i64 OFF_WQP = 69 * MB;    // bf16 512x512 row-perm o'=h*64+dk
constexpr i64 OFF_WKP = 69 * MB + 524288;
constexpr i64 OFF_WVP = 69 * MB + 1048576;
constexpr i64 OFF_WMT = 69 * MB + 1572864;  // bf16 [c'=512][o=512] Wm^T col-permuted
constexpr i64 OFF_W1A = 71 * MB;    // bf16 [1024][512] W1 cols 0:512
constexpr i64 OFF_W1C = 72 * MB;    // bf16 [1024][1024]: cols 0:512 = W1a*Wm, cols 512: = W1b
constexpr i64 OFF_W2B = 74 * MB;    // bf16 512x1024
constexpr i64 OFF_BQP = 75 * MB;    // f32 512 (permuted)
constexpr i64 OFF_BKP = 75 * MB + 2048;
constexpr i64 OFF_BVP = 75 * MB + 4096;
constexpr i64 OFF_BNA = 75 * MB + 8192;   // f32 1024 BN scale
constexpr i64 OFF_BNC = 75 * MB + 12288;  // f32 1024 BN shift (incl b1 AND W1a*bm)
constexpr i64 OFF_MSK = 76 * MB;    // bit-packed mask u32 [B][N][64] (u64 rows per mt)

DEV u16 f2bf(float f) {  // round-to-nearest-even f32->bf16
  u32 u = __float_as_uint(f);
  u = u + 0x7FFFu + ((u >> 16) & 1u);
  return (u16)(u >> 16);
}

DEV float bf2f(u16 u) { return __uint_as_float(((u32)u) << 16); }
DEV float bf2f32(u32 u) { return __uint_as_float(u << 16); }

// pack two f32 -> two bf16 (truncation) in ONE v_perm_b32; lo -> low 16 bits
DEV u32 packbf(float lo, float hi) {
  return __builtin_amdgcn_perm(__float_as_uint(hi), __float_as_uint(lo), 0x07060302u);
}

DEV float fexp2(float x) {
#if __has_builtin(__builtin_amdgcn_exp2f)
  return __builtin_amdgcn_exp2f(x);
#else
  return exp2f(x);
#endif
}

DEV bf16x8 ldfrag(const u16* p) {  // 16B-aligned LDS fragment load
  bf16x8 v;
  __builtin_memcpy(&v, __builtin_assume_aligned(p, 16), 16);
  return v;
}

DEV bf16x8 ldfrag2(const u16* p0, const u16* p1) {  // two 8B LDS loads -> one frag
  bf16x8 v;
  __builtin_memcpy(&v, __builtin_assume_aligned(p0, 8), 8);
  __builtin_memcpy((char*)&v + 8, __builtin_assume_aligned(p1, 8), 8);
  return v;
}

DEV bf16x8 ones8() {  // bf16 1.0 x8
  u16x8 u = {0x3F80, 0x3F80, 0x3F80, 0x3F80, 0x3F80, 0x3F80, 0x3F80, 0x3F80};
  bf16x8 v;
  __builtin_memcpy(&v, &u, 16);
  return v;
}

// async global->LDS, 16B per lane; LDS dest = wave-uniform base + lane*16
DEV void gload16(const void* g, void* lds) {
  __builtin_amdgcn_global_load_lds((__attribute__((address_space(1))) void*)g,
                                   (__attribute__((address_space(3))) void*)lds, 16, 0, 0);
}

DEV f32x4 mfma16(bf16x8 a, bf16x8 b, f32x4 c) {
  return __builtin_amdgcn_mfma_f32_16x16x32_bf16(a, b, c, 0, 0, 0);
}

DEV f32x16 mfma32(bf16x8 a, bf16x8 b, f32x16 c) {
  return __builtin_amdgcn_mfma_f32_32x32x16_bf16(a, b, c, 0, 0, 0);
}

// ---------------- prep_all: weights, BN fold, mask pack, input transpose ----------------
__global__ __launch_bounds__(256) void prep_all(
    const float* __restrict__ Wq, const float* __restrict__ Wk, const float* __restrict__ Wv,
    const float* __restrict__ Wm, const float* __restrict__ W1, const float* __restrict__ W2,
    const float* __restrict__ bq, const float* __restrict__ bk, const float* __restrict__ bv,
    const float* __restrict__ bm, const float* __restrict__ b1, const float* __restrict__ gamma_,
    const float* __restrict__ beta_, const float* __restrict__ rmean,
    const float* __restrict__ rvar, const int* __restrict__ mask,
    const float* __restrict__ iq, const float* __restrict__ kt, const float* __restrict__ vv,
    u16* __restrict__ wqp, u16* __restrict__ wkp, u16* __restrict__ wvp, u16* __restrict__ wmt,
    u16* __restrict__ w1a, u16* __restrict__ w1c, u16* __restrict__ w2b,
    float* __restrict__ bqp, float* __restrict__ bkp, float* __restrict__ bvp,
    float* __restrict__ bna, float* __restrict__ bnc, u32* __restrict__ mw,
    u16* __restrict__ cat, u16* __restrict__ xkt, u16* __restrict__ xvt) {
  __shared__ float tile[32][33];
  const int blk = blockIdx.x, t = threadIdx.x;
  if (blk < 768) {  // Wq/Wk/Wv row-permute: dst row o'=h*64+dk <- src row dk*8+h
    const int which = blk >> 8, lb = blk & 255;
    const float* W = which == 0 ? Wq : (which == 1 ? Wk : Wv);
    u16* dst = which == 0 ? wqp : (which == 1 ? wkp : wvp);
    for (int e = lb * 256 + t; e < 262144; e += 65536) {
      int op = e >> 9, i = e & 511;
      int dk = op & 63, h = op >> 6;
      dst[e] = f2bf(W[(dk * 8 + h) * 512 + i]);
    }
  } else if (blk < 1024) {  // wmt[c'][o] = Wm[o][dk*8+h], c'=h*64+dk
    const int lb = blk - 768;
    for (int e = lb * 256 + t; e < 262144; e += 65536) {
      int cp = e >> 9, o = e & 511;
      int dk = cp & 63, h = cp >> 6;
      wmt[e] = f2bf(Wm[o * 512 + dk * 8 + h]);
    }
  } else if (blk < 1280) {  // w1a = W1[:, 0:512]
    const int lb = blk - 1024;
    for (int e = lb * 256 + t; e < 524288; e += 65536) {
      int row = e >> 9, o = e & 511;
      w1a[e] = f2bf(W1[(i64)row * 1024 + o]);
    }
  } else if (blk < 1536) {  // w1c[:, 512:1024] = W1[:, 512:1024]
    const int lb = blk - 1280;
    for (int e = lb * 256 + t; e < 524288; e += 65536) {
      int row = e >> 9, j = e & 511;
      w1c[(i64)row * 1024 + 512 + j] = f2bf(W1[(i64)row * 1024 + 512 + j]);
    }
  } else if (blk < 1792) {  // W2
    const int lb = blk - 1536;
    for (int e = lb * 256 + t; e < 524288; e += 65536) w2b[e] = f2bf(W2[e]);
  } else if (blk < 1808) {  // BN fold incl. s_e = sum_o W1a[e][o]*bm[o]
    __shared__ float sm[4][64];
    const int base = (blk - 1792) * 64;
    const int el = t & 63, oq = t >> 6;
    const float* wrow = W1 + (i64)(base + el) * 1024 + oq * 128;
    const float* bmq = bm + oq * 128;
    float s = 0.f;
#pragma unroll 8
    for (int j = 0; j < 128; j += 4) {
      float4 x = *(const float4*)(wrow + j);
      float4 y = *(const float4*)(bmq + j);
      s += x.x * y.x + x.y * y.y + x.z * y.z + x.w * y.w;
    }
    sm[oq][el] = s;
    __syncthreads();
    if (t < 64) {
      int e = base + t;
      float a = gamma_[e] * rsqrtf(rvar[e] + 1e-5f);
      bna[e] = a;
      bnc[e] = (b1[e] - rmean[e]) * a + beta_[e] + a * (sm[0][t] + sm[1][t] + sm[2][t] + sm[3][t]);
    }
  } else if (blk == 1808) {  // permuted projection biases
    for (int e = t; e < 512; e += 256) {
      int src = (e & 63) * 8 + (e >> 6);
      bqp[e] = bq[src]; bkp[e] = bk[src]; bvp[e] = bv[src];
    }
  } else if (blk < 2833) {  // mask pack: each lane packs its own 32 consecutive ints -> one u32
    const int tid = (blk - 1809) * 256 + t;  // [0, 262144)
    const i64 base = (i64)tid * 32;
    const int4* mp = (const int4*)(mask + base);
    u32 word = 0;
#pragma unroll
    for (int j = 0; j < 8; ++j) {
      int4 x = mp[j];
      u32 nib = (x.x != 0 ? 1u : 0u) | (x.y != 0 ? 2u : 0u) | (x.z != 0 ? 4u : 0u) |
                (x.w != 0 ? 8u : 0u);
      word |= nib << (j * 4);
    }
    mw[tid] = word;
  } else {  // transpose+convert: (B,D,N) f32 -> (B,N,D) bf16, packed u32 stores
    const int idx = blk - 2833;
    const int bx = idx & 63, by = (idx >> 6) & 15, bz = idx >> 10;
    const int tensor = bz >> 1, b = bz & 1;
    const float* src = (tensor == 0 ? iq : (tensor == 1 ? kt : vv)) + (i64)b * DD * NN;
    u16* dst; i64 ldd; int coff;
    if (tensor == 0)      { dst = cat + (i64)b * NN * D2; ldd = D2; coff = DD; }
    else if (tensor == 1) { dst = xkt + (i64)b * NN * DD; ldd = DD; coff = 0; }
    else                  { dst = xvt + (i64)b * NN * DD; ldd = DD; coff = 0; }
    const int x0 = bx * 32, y0 = by * 32;
    const int col = t & 31, rg = t >> 5;
#pragma unroll
    for (int i = 0; i < 4; ++i) {
      int row = rg + i * 8;
      tile[row][col] = src[(i64)(y0 + row) * NN + x0 + col];
    }
    __syncthreads();
    const int dp = t & 15, rbase = t >> 4;
    u32* dst32 = (u32*)dst;
    const i64 ldw = ldd >> 1;
    const int cw = (coff + y0) >> 1;
#pragma unroll
    for (int i = 0; i < 2; ++i) {
      int rr = rbase + i * 16;
      dst32[(i64)(x0 + rr) * ldw + cw + dp] = packbf(tile[2 * dp][rr], tile[2 * dp + 1][rr]);
    }
  }
}

// ---------------- shared GEMM core, 2-phase double-buffered ----------------
template <int AM, int AN>
DEV void gemm_core(const u16* __restrict__ A, i64 lda, const u16* __restrict__ Bp, i64 ldb,
                   int K, u16* As, u16* Bs, f32x4 (&acc)[AM][AN]) {
  constexpr int BM = AM * 32, BN = AN * 32;
  const int t = threadIdx.x, w = t >> 6, l = t & 63, quad = l >> 4, l15 = l & 15;
  const int wm = (w >> 1) * AM * 16, wn = (w & 1) * AN * 16;
  auto stage = [&](int kk, int buf) {
    u16* Ad = As + buf * (BM * 64);
    u16* Bd = Bs + buf * (BN * 64);
#pragma unroll
    for (int j = 0; j < BM / 32; ++j) {
      int ch = j * 256 + w * 64 + l, r = ch >> 3, c = ch & 7;
      gload16(A + (i64)r * lda + kk + ((c ^ (r & 7)) << 3), Ad + (j * 256 + w * 64) * 8);
    }
#pragma unroll
    for (int j = 0; j < BN / 32; ++j) {
      int ch = j * 256 + w * 64 + l, r = ch >> 3, c = ch & 7;
      gload16(Bp + (i64)r * ldb + kk + ((c ^ (r & 7)) << 3), Bd + (j * 256 + w * 64) * 8);
    }
  };
  const int nst = K >> 6;
  stage(0, 0);
  asm volatile("s_waitcnt vmcnt(0)" ::: "memory");
  __builtin_amdgcn_s_barrier();
  for (int s = 0; s < nst; ++s) {
    if (s + 1 < nst) stage((s + 1) << 6, (s + 1) & 1);  // prefetch overlaps MFMA below
    const u16* Ac = As + (s & 1) * (BM * 64);
    const u16* Bc = Bs + (s & 1) * (BN * 64);
#pragma unroll
    for (int kc = 0; kc < 2; ++kc) {
      const int sw = ((kc * 4 + quad) ^ (l15 & 7)) << 3;
      bf16x8 af[AM], bfr[AN];
#pragma unroll
      for (int i = 0; i < AM; ++i) af[i] = ldfrag(&Ac[(wm + i * 16 + l15) * 64 + sw]);
#pragma unroll
      for (int j = 0; j < AN; ++j) bfr[j] = ldfrag(&Bc[(wn + j * 16 + l15) * 64 + sw]);
#pragma unroll
      for (int i = 0; i < AM; ++i)
#pragma unroll
        for (int j = 0; j < AN; ++j) acc[i][j] = mfma16(af[i], bfr[j], acc[i][j]);
    }
    asm volatile("s_waitcnt vmcnt(0) lgkmcnt(0)" ::: "memory");
    __builtin_amdgcn_s_barrier();
  }
}

// ---------------- fused Q/K/V projection + Wc weight-GEMM, 128x128 tiles, flat grid 416 ----------------
__global__ __launch_bounds__(256) void qkv_gemm(const u16* __restrict__ cat,
                                                const u16* __restrict__ xkt,
                                                const u16* __restrict__ xvt,
                                                const u16* __restrict__ wqp,
                                                const u16* __restrict__ wkp,
                                                const u16* __restrict__ wvp,
                                                const u16* __restrict__ w1a,
                                                const u16* __restrict__ wmt,
                                                const float* __restrict__ bqp,
                                                const float* __restrict__ bkp,
                                                const float* __restrict__ bvp,
                                                u16* __restrict__ qh, u16* __restrict__ kh,
                                                u16* __restrict__ vt, u16* __restrict__ w1c) {
  __shared__ __align__(16) u16 As[2 * 128 * 64];
  __shared__ __align__(16) u16 Bs[2 * 128 * 64];
  const int flat = blockIdx.x;
  const int t = threadIdx.x, w = t >> 6, l = t & 63, quad = l >> 4, l15 = l & 15;
  const int wm = (w >> 1) * 64, wn = (w & 1) * 64;
  int op, b = 0, mx, ny;
  if (flat < 256) {        // Q (0..127) / K (128..255): M=2048, N=512 -> 16x4 per b
    op = flat >> 7;
    b = (flat >> 6) & 1;
    const int r = flat & 63;
    mx = r >> 2; ny = r & 3;
  } else if (flat < 384) {  // V: M=512, N=2048 -> 4x16 per b
    op = 2;
    const int r = flat - 256;
    b = r >> 6;
    const int rr = r & 63;
    mx = rr >> 4; ny = rr & 15;
  } else {                  // Wc: M=1024, N=512 -> 8x4
    op = 3;
    const int r = flat - 384;
    mx = r >> 2; ny = r & 3;
  }
  const u16 *A, *Bp;
  i64 lda, ldb;
  if (op < 2) {
    A = (op == 0 ? cat + DD : xkt);
    lda = (op == 0 ? D2 : DD);
    A += (i64)b * NN * lda + (i64)mx * 128 * lda;
    Bp = (op == 0 ? wqp : wkp) + (i64)ny * 128 * DD;
    ldb = DD;
  } else if (op == 2) {
    A = wvp + (i64)mx * 128 * DD; lda = DD;
    Bp = xvt + (i64)b * NN * DD + (i64)ny * 128 * DD; ldb = DD;
  } else {
    A = w1a + (i64)mx * 128 * DD; lda = DD;
    Bp = wmt + (i64)ny * 128 * DD; ldb = DD;
  }
  f32x4 acc[4][4] = {};
  gemm_core<4, 4>(A, lda, Bp, ldb, DD, As, Bs, acc);

  const int rowBase = mx * 128 + wm + quad * 4;
  const int colBase = ny * 128 + wn + l15;
  if (op < 2) {  // head scatter: col=h*64+dk -> [b][h][n][dk]; Q scaled by QSC
    const float* bias = (op == 0 ? bqp : bkp);
    const float sc = (op == 0 ? QSC : 1.f);
    u16* dst = (op == 0 ? qh : kh) + (i64)b * HH * NN * DKc;
#pragma unroll
    for (int j = 0; j < 4; ++j) {
      const int col = colBase + j * 16;
      const float cA = bias[col];
#pragma unroll
      for (int i = 0; i < 4; ++i)
#pragma unroll
        for (int r = 0; r < 4; ++r) {
          const int row = rowBase + i * 16 + r;
          dst[(i64)(col >> 6) * (NN * 64) + (i64)row * 64 + (col & 63)] =
              f2bf((acc[i][j][r] + cA) * sc);
        }
    }
  } else if (op == 2) {  // V: row bias, store [b][o'][m] (natural m)
    u16* dst = vt + (i64)b * HH * DKc * NN;
#pragma unroll
    for (int j = 0; j < 4; ++j) {
      const int col = colBase + j * 16;
#pragma unroll
      for (int i = 0; i < 4; ++i)
#pragma unroll
        for (int r = 0; r < 4; ++r) {
          const int row = rowBase + i * 16 + r;
          dst[(i64)row * NN + col] = f2bf(acc[i][j][r] + bvp[row]);
        }
    }
  } else {  // Wc plain store -> w1c[:, 0:512]
#pragma unroll
    for (int j = 0; j < 4; ++j) {
      const int col = colBase + j * 16;
#pragma unroll
      for (int i = 0; i < 4; ++i)
#pragma unroll
        for (int r = 0; r < 4; ++r) {
          const int row = rowBase + i * 16 + r;
          w1c[(i64)row * D2 + col] = f2bf(acc[i][j][r]);
        }
    }
  }
}

// ---------------- generic gemm_bt: C[m][n] = A[m][:]·B[n][:] (+epilogue) ----------------
struct GArgs {
  const u16* A; i64 lda, sAb;
  const u16* B; i64 ldb, sBb;
  void* C; i64 ldc, sCb;
  const float* p1; const float* p2;
  int K;
};

template <int MODE, int AM, int AN, int SWZ>
__global__ __launch_bounds__(256) void gemm_bt(GArgs g) {
  __shared__ __align__(16) u16 As[2 * AM * 32 * 64];
  __shared__ __align__(16) u16 Bs[2 * AN * 32 * 64];
  const int t = threadIdx.x, w = t >> 6, l = t & 63, quad = l >> 4, l15 = l & 15;
  const int wm = (w >> 1) * AM * 16, wn = (w & 1) * AN * 16;
  int bx = blockIdx.x, by = blockIdx.y, bz = blockIdx.z;
  if (SWZ == 1) {  // flat = bx + 8by + 256bz; pin same-by blocks to one XCD slot
    const int i = bx + (by << 3) + (bz << 8);
    const int slot = i & 7, jj = i >> 3;
    by = slot + ((jj & 3) << 3);
    const int j2 = jj >> 2;
    bx = j2 & 7;
    bz = j2 >> 3;
  }
  const u16* A = g.A + (i64)bz * g.sAb + (i64)bx * (AM * 32) * g.lda;
  const u16* Bp = g.B + (i64)bz * g.sBb + (i64)by * (AN * 32) * g.ldb;
  f32x4 acc[AM][AN] = {};
  gemm_core<AM, AN>(A, g.lda, Bp, g.ldb, g.K, As, Bs, acc);

  const int rowBase = bx * (AM * 32) + wm + quad * 4;
  const int colBase = by * (AN * 32) + wn + l15;
#pragma unroll
  for (int j = 0; j < AN; ++j) {
    const int col = colBase + j * 16;
    float cA = 0.f, cB = 0.f;
    if (MODE == 3) { cA = g.p1[col]; cB = g.p2[col]; }
#pragma unroll
    for (int i = 0; i < AM; ++i) {
#pragma unroll
      for (int r = 0; r < 4; ++r) {
        const int row = rowBase + i * 16 + r;
        float v = acc[i][j][r];
        if (MODE == 3) {  // BN+ReLU, bf16 out
          float x = v * cA + cB;
          ((u16*)g.C + (i64)bz * g.sCb)[(i64)row * g.ldc + col] = f2bf(x > 0.f ? x : 0.f);
        } else {  // MODE 4: fp32 out, row bias (W2 -> d_out)
          ((float*)g.C + (i64)bz * g.sCb)[(i64)row * g.ldc + col] = v + g.p1[row];
        }
      }
    }
  }
}

// ---------------- flash attention v16: 2 blocks/CU (cross-block latency hiding) ----------------
// Same total work/waves as v15 but each v15 block split in half: 512 blocks x 256 threads
// (4 waves = 2 q-groups x 2 kv-halves), 64 q-rows x full 2048 kv per block, LDS 64KB ->
// EXACTLY 2 blocks/CU. Flash was the only kernel at 1 block/CU: every __syncthreads
// (vmcnt(0) drain) stalled the whole CU. With a co-resident second block, its compute
// issues during our stage-wait (the m114 overlap that made all GEMM scheduling moot).
// Cost: 2x staging redundancy (L2-resident reads, ~10 TB/s aggregate << 34.5 L2 ceiling) —
// paying bandwidth for latency-hiding in a kernel at 6% HBM / 15% MFMA.
// Tail: in-LDS combine (intra-block halves), unchanged arithmetic.
__global__ __launch_bounds__(256) void flash_attn(const u16* __restrict__ Qh,
                                                  const u16* __restrict__ Kh,
                                                  const u16* __restrict__ Vt,
                                                  const u64* __restrict__ MW64,
                                                  u16* __restrict__ cat) {
  // 64KB: pair-slot S0 = {K(t) V(t) K(t+1) V(t+1)}, pair-slot S1 likewise
  __shared__ __align__(16) u16 smem[4 * 8192];
  u16* S0 = smem;
  u16* S1 = smem + 16384;
  const int t = threadIdx.x, w = t >> 6, l = t & 63, l31 = l & 31, lh = l >> 5;
  // flat decode pinning all blocks of head h to one XCD slot (RR dispatch, 512 blocks)
  const int flat = blockIdx.x;
  const int h = flat & 7;
  const int j = flat >> 3;             // [0,64)
  const int nt = j & 31, b = j >> 5;   // 32 q-chunks of 64 rows
  const int g = w & 1, half = w >> 1;  // q-group (2), kv-half of each tile (2)
  const int nl = g * 32 + l31;         // local q row [0,64)
  const int n = nt * 64 + nl;          // global q row
  const u16* Qb = Qh + ((i64)(b * HH + h) * NN + nt * 64 + g * 32) * 64;
  const u16* Kb = Kh + (i64)(b * HH + h) * NN * 64;
  const u16* Vb = Vt + (i64)(b * HH + h) * 64 * NN;
  const u64* mwp = MW64 + (i64)(b * NN + n) * 32;
  const bf16x8 ONE = ones8();
  // Q fragments (B-operand): lane q=l31, k = kc*16 + lh*8 + j
  bf16x8 qf[4];
#pragma unroll
  for (int kc = 0; kc < 4; ++kc)
    __builtin_memcpy(&qf[kc], Qb + (i64)l31 * 64 + kc * 16 + lh * 8, 16);

  f32x16 oacc0 = {}, oacc1 = {}, lacc = {};
  const int hrow = half * 32 + l31;  // K LDS row this wave reads
  const int sw = l31 & 7;

  // 256 threads cover a 64x64 K tile + V tile in TWO gload16 pairs per thread
  auto stage = [&](u16* Kd, u16* Vd, int mt) {
#pragma unroll
    for (int i = 0; i < 2; ++i) {
      const int ch = i * 256 + t, r = ch >> 3, c = ch & 7;
      gload16(Kb + (i64)(mt * 64 + r) * 64 + ((c ^ (r & 7)) << 3), Kd + ch * 8);
      gload16(Vb + (i64)r * NN + mt * 64 + ((c ^ (r & 7)) << 3), Vd + ch * 8);
    }
  };
  auto stage_pair = [&](u16* S, int mt) {
    stage(S, S + 4096, mt);
    stage(S + 8192, S + 12288, mt + 1);
  };
  // this wave's kv-half of ONE tile
  auto compute_half = [&](const u16* Kc, const u16* Vc, int mt) {
    f32x16 s = {};
    __builtin_amdgcn_s_setprio(1);
#pragma unroll
    for (int kc = 0; kc < 4; ++kc) {
      bf16x8 k0 = ldfrag(&Kc[hrow * 64 + (((kc * 2 + lh) ^ sw) << 3)]);
      s = mfma32(k0, qf[kc], s);
    }
    __builtin_amdgcn_s_setprio(0);
    const u64 mrow = mwp[mt];
    u32 pw[8];
#pragma unroll
    for (int k = 0; k < 8; ++k) {
      const int kvb = ((2 * k) & 3) + 8 * ((2 * k) >> 2) + 4 * lh;
      const u32 m2 = (u32)(mrow >> (kvb + half * 32));
      const u32 mA = ((m2 & 1u) | ((m2 & 2u) << 15)) * 0xFFFFu;
      pw[k] = packbf(fexp2(s[2 * k]), fexp2(s[2 * k + 1])) & mA;
    }
    bf16x8 pf[2];
#pragma unroll
    for (int c = 0; c < 2; ++c) __builtin_memcpy(&pf[c], &pw[c * 4], 16);
    __builtin_amdgcn_s_setprio(1);
    lacc = mfma32(ONE, pf[0], lacc);
    lacc = mfma32(ONE, pf[1], lacc);
#pragma unroll
    for (int cc = 0; cc < 2; ++cc) {
      const int ch0 = 2 * (2 * half + cc), ch1 = ch0 + 1;
      const u16* r0 = &Vc[l31 * 64];
      const u16* r1 = &Vc[(32 + l31) * 64];
      bf16x8 v0 = ldfrag2(r0 + ((ch0 ^ sw) << 3) + lh * 4, r0 + ((ch1 ^ sw) << 3) + lh * 4);
      bf16x8 v1 = ldfrag2(r1 + ((ch0 ^ sw) << 3) + lh * 4, r1 + ((ch1 ^ sw) << 3) + lh * 4);
      oacc0 = mfma32(v0, pf[cc], oacc0);
      oacc1 = mfma32(v1, pf[cc], oacc1);
    }
    __builtin_amdgcn_s_setprio(0);
  };
  auto compute_pair = [&](const u16* S, int mt) {
    compute_half(S, S + 4096, mt);
    compute_half(S + 8192, S + 12288, mt + 1);
  };

  stage_pair(S0, 0);
  for (int ii = 0; ii < 8; ++ii) {   // 32 tiles = 16 pairs, dbuf at pair granularity
    const int m = 4 * ii;
    __syncthreads();                 // drains vmcnt -> S0 pair ready
    stage_pair(S1, m + 2);           // prefetch overlaps compute below
    compute_pair(S0, m);
    __syncthreads();                 // drains vmcnt -> S1 pair ready
    if (ii < 7) stage_pair(S0, m + 4);
    compute_pair(S1, m + 2);
  }

  // ---- fused combine, all intra-block ----
  __syncthreads();  // compute done; LDS free
  u32* ex = (u32*)smem;                         // [64 nl][32 dp] u32, XOR-swizzled (8KB)
  float* exl = (float*)((char*)smem + 8192);    // [64] f32 partial row-sums
  if (half == 1) {  // deposit partial O (bf16-packed, same precision as old global path) + l
#pragma unroll
    for (int e = 0; e < 8; ++e) {
      const int r0 = 2 * e, r1 = r0 + 1;
      const int dp = ((r0 & 3) + 8 * (r0 >> 2) + 4 * lh) >> 1;
      ex[nl * 32 + (dp ^ (nl & 31))] = packbf(oacc0[r0], oacc0[r1]);
      ex[nl * 32 + ((dp + 16) ^ (nl & 31))] = packbf(oacc1[r0], oacc1[r1]);
    }
    if (lh == 0) exl[nl] = lacc[0];
  }
  __syncthreads();
  u32* lt = (u32*)((char*)smem + 16384);        // transpose buffer (8KB)
  if (half == 0) {  // fold partner, normalize, swizzled transpose write
    const float lsum = lacc[0] + exl[nl];
    const float rl = __builtin_amdgcn_rcpf(lsum);
#pragma unroll
    for (int e = 0; e < 8; ++e) {
      const int r0 = 2 * e, r1 = r0 + 1;
      const int dp = ((r0 & 3) + 8 * (r0 >> 2) + 4 * lh) >> 1;
      const u32 va = ex[nl * 32 + (dp ^ (nl & 31))];
      const u32 vb = ex[nl * 32 + ((dp + 16) ^ (nl & 31))];
      lt[nl * 32 + (dp ^ (nl & 31))] =
          packbf((oacc0[r0] + bf2f32(va & 0xFFFFu)) * rl, (oacc0[r1] + bf2f32(va >> 16)) * rl);
      lt[nl * 32 + ((dp + 16) ^ (nl & 31))] =
          packbf((oacc1[r0] + bf2f32(vb & 0xFFFFu)) * rl, (oacc1[r1] + bf2f32(vb >> 16)) * rl);
    }
  }
  __syncthreads();
  // coalesced writeout: 64 n-rows x 32 u32 into cat[:, 0:512)
  u32* catw = (u32*)cat;
#pragma unroll
  for (int i = 0; i < 8; ++i) {
    const int idx = i * 256 + t;  // [0, 2048)
    const int nn = idx >> 5, dp = idx & 31;
    catw[((i64)b * NN + nt * 64 + nn) * (D2 / 2) + h * 32 + dp] = lt[nn * 32 + (dp ^ (nn & 31))];
  }
}

extern "C" void kernel_launch(void* const* d_in, const int* in_sizes, int n_in,
                              void* d_out, int out_size, void* d_ws, size_t ws_size,
                              hipStream_t stream) {
  (void)in_sizes; (void)n_in; (void)out_size; (void)ws_size;
  const float* iq    = (const float*)d_in[0];
  const float* kt    = (const float*)d_in[1];
  const float* vv    = (const float*)d_in[2];
  const int*   mask  = (const int*)d_in[3];
  const float* Wq    = (const float*)d_in[4];
  const float* bq    = (const float*)d_in[5];
  const float* Wk    = (const float*)d_in[6];
  const float* bk    = (const float*)d_in[7];
  const float* Wv    = (const float*)d_in[8];
  const float* bv    = (const float*)d_in[9];
  const float* Wm    = (const float*)d_in[10];
  const float* bm    = (const float*)d_in[11];
  const float* W1    = (const float*)d_in[12];
  const float* b1    = (const float*)d_in[13];
  const float* gamma_= (const float*)d_in[14];
  const float* beta_ = (const float*)d_in[15];
  const float* rmean = (const float*)d_in[16];
  const float* rvar  = (const float*)d_in[17];
  const float* W2    = (const float*)d_in[18];
  const float* b2    = (const float*)d_in[19];

  char* ws = (char*)d_ws;
  u16* cat = (u16*)(ws + OFF_CAT);
  u16* xkt = (u16*)(ws + OFF_XKT);
  u16* xvt = (u16*)(ws + OFF_XVT);
  u16* qh  = (u16*)(ws + OFF_QH);
  u16* kh  = (u16*)(ws + OFF_KH);
  u16* vt  = (u16*)(ws + OFF_VT);
  u16* ht  = (u16*)(ws + OFF_HT);
  u16* wqp = (u16*)(ws + OFF_WQP);
  u16* wkp = (u16*)(ws + OFF_WKP);
  u16* wvp = (u16*)(ws + OFF_WVP);
  u16* wmt = (u16*)(ws + OFF_WMT);
  u16* w1a = (u16*)(ws + OFF_W1A);
  u16* w1c = (u16*)(ws + OFF_W1C);
  u16* w2b = (u16*)(ws + OFF_W2B);
  float* bqp = (float*)(ws + OFF_BQP);
  float* bkp = (float*)(ws + OFF_BKP);
  float* bvp = (float*)(ws + OFF_BVP);
  float* bna = (float*)(ws + OFF_BNA);
  float* bnc = (float*)(ws + OFF_BNC);
  u32* mw = (u32*)(ws + OFF_MSK);

  // 1. prep (weights/BN/mask) + input transpose, one launch
  prep_all<<<8977, 256, 0, stream>>>(Wq, Wk, Wv, Wm, W1, W2, bq, bk, bv, bm, b1, gamma_, beta_,
                                     rmean, rvar, mask, iq, kt, vv, wqp, wkp, wvp, wmt, w1a, w1c,
                                     w2b, bqp, bkp, bvp, bna, bnc, mw, cat, xkt, xvt);
  // 2. fused Q/K/V projections + Wc, 128x128 tiles, flat grid (2-phase dbuf core)
  qkv_gemm<<<416, 256, 0, stream>>>(cat, xkt, xvt, wqp, wkp, wvp, w1a, wmt,
                                    bqp, bkp, bvp, qh, kh, vt, w1c);
  // 3. flash v16: 512 blocks x 256 threads, 2 blocks/CU, fused in-LDS combine
  flash_attn<<<512, 256, 0, stream>>>(qh, kh, vt, (const u64*)mw, cat);
  // 4. W1' + BN + ReLU, batch-merged M=4096, 128x64 tiles (2-phase dbuf core)
  GArgs wa{cat, D2, 0, w1c, D2, 0, ht, D2, 0, bna, bnc, D2};
  gemm_bt<3, 4, 2, 0><<<dim3(32, 16, 1), 256, 0, stream>>>(wa);
  // 5. W2 -> d_out (fp32), B-tiles XCD-pinned via SWZ (2-phase dbuf core)
  GArgs w2a{w2b, D2, 0, ht, D2, (i64)NN * D2, d_out, NN, (i64)DD * NN, b2, nullptr, D2};
  gemm_bt<4, 2, 2, 1><<<dim3(8, 32, 2), 256, 0, stream>>>(w2a);
}

// Round 9
// 210.164 us; speedup vs baseline: 1.0099x; 1.0099x over previous
//
#include <hip/hip_runtime.h>

typedef unsigned short u16;
typedef unsigned int u32;
typedef unsigned long long u64;
typedef long long i64;
typedef __bf16 bf16x8 __attribute__((ext_vector_type(8)));
typedef u16 u16x8 __attribute__((ext_vector_type(8)));
typedef float f32x4 __attribute__((ext_vector_type(4)));
typedef float f32x16 __attribute__((ext_vector_type(16)));

#define DEV __device__ __forceinline__

// problem constants (fixed by harness)
constexpr int BB = 2, DD = 512, NN = 2048, HH = 8, DKc = 64, D2 = 1024;

// Q pre-scale: 1/sqrt(64) * log2(e)  (folded into Q so softmax uses native exp2)
constexpr float QSC = 0.125f * 1.44269504088896340736f;

// workspace byte offsets (16B aligned); NO aliasing
constexpr i64 MB = 1048576;
constexpr i64 OFF_CAT = 0;          // bf16 [B][N][D2]; [0:512)=attn (flash tail), [512:1024)=iq^T
constexpr i64 OFF_XKT = 8 * MB;     // bf16 [B][N][D] key_t^T
constexpr i64 OFF_XVT = 12 * MB;    // bf16 [B][N][D] value^T
constexpr i64 OFF_QH  = 16 * MB;    // bf16 [B][H][N][DK] (Q pre-scaled by QSC)
constexpr i64 OFF_KH  = 20 * MB;    // bf16 [B][H][N][DK]
constexpr i64 OFF_VT  = 24 * MB;    // bf16 [B][H][DK][N]  (natural m)
constexpr i64 OFF_HT  = 28 * MB;    // bf16 [B][N][D2]
constexpr i64 OFF_WQP = 69 * MB;    // bf16 512x512 row-perm o'=h*64+dk
constexpr i64 OFF_WKP = 69 * MB + 524288;
constexpr i64 OFF_WVP = 69 * MB + 1048576;
constexpr i64 OFF_WMT = 69 * MB + 1572864;  // bf16 [c'=512][o=512] Wm^T col-permuted
constexpr i64 OFF_W1A = 71 * MB;    // bf16 [1024][512] W1 cols 0:512
constexpr i64 OFF_W1C = 72 * MB;    // bf16 [1024][1024]: cols 0:512 = W1a*Wm, cols 512: = W1b
constexpr i64 OFF_W2B = 74 * MB;    // bf16 512x1024
constexpr i64 OFF_BQP = 75 * MB;    // f32 512 (permuted)
constexpr i64 OFF_BKP = 75 * MB + 2048;
constexpr i64 OFF_BVP = 75 * MB + 4096;
constexpr i64 OFF_BNA = 75 * MB + 8192;   // f32 1024 BN scale
constexpr i64 OFF_BNC = 75 * MB + 12288;  // f32 1024 BN shift (incl b1 AND W1a*bm)
constexpr i64 OFF_MSK = 76 * MB;    // bit-packed mask u32 [B][N][64] (u64 rows per mt)

DEV u16 f2bf(float f) {  // round-to-nearest-even f32->bf16
  u32 u = __float_as_uint(f);
  u = u + 0x7FFFu + ((u >> 16) & 1u);
  return (u16)(u >> 16);
}

DEV float bf2f(u16 u) { return __uint_as_float(((u32)u) << 16); }
DEV float bf2f32(u32 u) { return __uint_as_float(u << 16); }

// pack two f32 -> two bf16 (truncation) in ONE v_perm_b32; lo -> low 16 bits
DEV u32 packbf(float lo, float hi) {
  return __builtin_amdgcn_perm(__float_as_uint(hi), __float_as_uint(lo), 0x07060302u);
}

DEV float fexp2(float x) {
#if __has_builtin(__builtin_amdgcn_exp2f)
  return __builtin_amdgcn_exp2f(x);
#else
  return exp2f(x);
#endif
}

DEV bf16x8 ldfrag(const u16* p) {  // 16B-aligned LDS fragment load
  bf16x8 v;
  __builtin_memcpy(&v, __builtin_assume_aligned(p, 16), 16);
  return v;
}

DEV bf16x8 ldfrag2(const u16* p0, const u16* p1) {  // two 8B LDS loads -> one frag
  bf16x8 v;
  __builtin_memcpy(&v, __builtin_assume_aligned(p0, 8), 8);
  __builtin_memcpy((char*)&v + 8, __builtin_assume_aligned(p1, 8), 8);
  return v;
}

DEV bf16x8 ones8() {  // bf16 1.0 x8
  u16x8 u = {0x3F80, 0x3F80, 0x3F80, 0x3F80, 0x3F80, 0x3F80, 0x3F80, 0x3F80};
  bf16x8 v;
  __builtin_memcpy(&v, &u, 16);
  return v;
}

// async global->LDS, 16B per lane; LDS dest = wave-uniform base + lane*16
DEV void gload16(const void* g, void* lds) {
  __builtin_amdgcn_global_load_lds((__attribute__((address_space(1))) void*)g,
                                   (__attribute__((address_space(3))) void*)lds, 16, 0, 0);
}

DEV f32x4 mfma16(bf16x8 a, bf16x8 b, f32x4 c) {
  return __builtin_amdgcn_mfma_f32_16x16x32_bf16(a, b, c, 0, 0, 0);
}

DEV f32x16 mfma32(bf16x8 a, bf16x8 b, f32x16 c) {
  return __builtin_amdgcn_mfma_f32_32x32x16_bf16(a, b, c, 0, 0, 0);
}

// ---------------- prep_all: weights, BN fold, mask pack, input transpose ----------------
__global__ __launch_bounds__(256) void prep_all(
    const float* __restrict__ Wq, const float* __restrict__ Wk, const float* __restrict__ Wv,
    const float* __restrict__ Wm, const float* __restrict__ W1, const float* __restrict__ W2,
    const float* __restrict__ bq, const float* __restrict__ bk, const float* __restrict__ bv,
    const float* __restrict__ bm, const float* __restrict__ b1, const float* __restrict__ gamma_,
    const float* __restrict__ beta_, const float* __restrict__ rmean,
    const float* __restrict__ rvar, const int* __restrict__ mask,
    const float* __restrict__ iq, const float* __restrict__ kt, const float* __restrict__ vv,
    u16* __restrict__ wqp, u16* __restrict__ wkp, u16* __restrict__ wvp, u16* __restrict__ wmt,
    u16* __restrict__ w1a, u16* __restrict__ w1c, u16* __restrict__ w2b,
    float* __restrict__ bqp, float* __restrict__ bkp, float* __restrict__ bvp,
    float* __restrict__ bna, float* __restrict__ bnc, u32* __restrict__ mw,
    u16* __restrict__ cat, u16* __restrict__ xkt, u16* __restrict__ xvt) {
  __shared__ float tile[32][33];
  const int blk = blockIdx.x, t = threadIdx.x;
  if (blk < 768) {  // Wq/Wk/Wv row-permute: dst row o'=h*64+dk <- src row dk*8+h
    const int which = blk >> 8, lb = blk & 255;
    const float* W = which == 0 ? Wq : (which == 1 ? Wk : Wv);
    u16* dst = which == 0 ? wqp : (which == 1 ? wkp : wvp);
    for (int e = lb * 256 + t; e < 262144; e += 65536) {
      int op = e >> 9, i = e & 511;
      int dk = op & 63, h = op >> 6;
      dst[e] = f2bf(W[(dk * 8 + h) * 512 + i]);
    }
  } else if (blk < 1024) {  // wmt[c'][o] = Wm[o][dk*8+h], c'=h*64+dk
    const int lb = blk - 768;
    for (int e = lb * 256 + t; e < 262144; e += 65536) {
      int cp = e >> 9, o = e & 511;
      int dk = cp & 63, h = cp >> 6;
      wmt[e] = f2bf(Wm[o * 512 + dk * 8 + h]);
    }
  } else if (blk < 1280) {  // w1a = W1[:, 0:512]
    const int lb = blk - 1024;
    for (int e = lb * 256 + t; e < 524288; e += 65536) {
      int row = e >> 9, o = e & 511;
      w1a[e] = f2bf(W1[(i64)row * 1024 + o]);
    }
  } else if (blk < 1536) {  // w1c[:, 512:1024] = W1[:, 512:1024]
    const int lb = blk - 1280;
    for (int e = lb * 256 + t; e < 524288; e += 65536) {
      int row = e >> 9, j = e & 511;
      w1c[(i64)row * 1024 + 512 + j] = f2bf(W1[(i64)row * 1024 + 512 + j]);
    }
  } else if (blk < 1792) {  // W2
    const int lb = blk - 1536;
    for (int e = lb * 256 + t; e < 524288; e += 65536) w2b[e] = f2bf(W2[e]);
  } else if (blk < 1808) {  // BN fold incl. s_e = sum_o W1a[e][o]*bm[o]
    __shared__ float sm[4][64];
    const int base = (blk - 1792) * 64;
    const int el = t & 63, oq = t >> 6;
    const float* wrow = W1 + (i64)(base + el) * 1024 + oq * 128;
    const float* bmq = bm + oq * 128;
    float s = 0.f;
#pragma unroll 8
    for (int j = 0; j < 128; j += 4) {
      float4 x = *(const float4*)(wrow + j);
      float4 y = *(const float4*)(bmq + j);
      s += x.x * y.x + x.y * y.y + x.z * y.z + x.w * y.w;
    }
    sm[oq][el] = s;
    __syncthreads();
    if (t < 64) {
      int e = base + t;
      float a = gamma_[e] * rsqrtf(rvar[e] + 1e-5f);
      bna[e] = a;
      bnc[e] = (b1[e] - rmean[e]) * a + beta_[e] + a * (sm[0][t] + sm[1][t] + sm[2][t] + sm[3][t]);
    }
  } else if (blk == 1808) {  // permuted projection biases
    for (int e = t; e < 512; e += 256) {
      int src = (e & 63) * 8 + (e >> 6);
      bqp[e] = bq[src]; bkp[e] = bk[src]; bvp[e] = bv[src];
    }
  } else if (blk < 2833) {  // mask pack: each lane packs its own 32 consecutive ints -> one u32
    const int tid = (blk - 1809) * 256 + t;  // [0, 262144)
    const i64 base = (i64)tid * 32;
    const int4* mp = (const int4*)(mask + base);
    u32 word = 0;
#pragma unroll
    for (int j = 0; j < 8; ++j) {
      int4 x = mp[j];
      u32 nib = (x.x != 0 ? 1u : 0u) | (x.y != 0 ? 2u : 0u) | (x.z != 0 ? 4u : 0u) |
                (x.w != 0 ? 8u : 0u);
      word |= nib << (j * 4);
    }
    mw[tid] = word;
  } else {  // transpose+convert: (B,D,N) f32 -> (B,N,D) bf16, packed u32 stores
    const int idx = blk - 2833;
    const int bx = idx & 63, by = (idx >> 6) & 15, bz = idx >> 10;
    const int tensor = bz >> 1, b = bz & 1;
    const float* src = (tensor == 0 ? iq : (tensor == 1 ? kt : vv)) + (i64)b * DD * NN;
    u16* dst; i64 ldd; int coff;
    if (tensor == 0)      { dst = cat + (i64)b * NN * D2; ldd = D2; coff = DD; }
    else if (tensor == 1) { dst = xkt + (i64)b * NN * DD; ldd = DD; coff = 0; }
    else                  { dst = xvt + (i64)b * NN * DD; ldd = DD; coff = 0; }
    const int x0 = bx * 32, y0 = by * 32;
    const int col = t & 31, rg = t >> 5;
#pragma unroll
    for (int i = 0; i < 4; ++i) {
      int row = rg + i * 8;
      tile[row][col] = src[(i64)(y0 + row) * NN + x0 + col];
    }
    __syncthreads();
    const int dp = t & 15, rbase = t >> 4;
    u32* dst32 = (u32*)dst;
    const i64 ldw = ldd >> 1;
    const int cw = (coff + y0) >> 1;
#pragma unroll
    for (int i = 0; i < 2; ++i) {
      int rr = rbase + i * 16;
      dst32[(i64)(x0 + rr) * ldw + cw + dp] = packbf(tile[2 * dp][rr], tile[2 * dp + 1][rr]);
    }
  }
}

// ---------------- shared GEMM core, 2-phase double-buffered ----------------
template <int AM, int AN>
DEV void gemm_core(const u16* __restrict__ A, i64 lda, const u16* __restrict__ Bp, i64 ldb,
                   int K, u16* As, u16* Bs, f32x4 (&acc)[AM][AN]) {
  constexpr int BM = AM * 32, BN = AN * 32;
  const int t = threadIdx.x, w = t >> 6, l = t & 63, quad = l >> 4, l15 = l & 15;
  const int wm = (w >> 1) * AM * 16, wn = (w & 1) * AN * 16;
  auto stage = [&](int kk, int buf) {
    u16* Ad = As + buf * (BM * 64);
    u16* Bd = Bs + buf * (BN * 64);
#pragma unroll
    for (int j = 0; j < BM / 32; ++j) {
      int ch = j * 256 + w * 64 + l, r = ch >> 3, c = ch & 7;
      gload16(A + (i64)r * lda + kk + ((c ^ (r & 7)) << 3), Ad + (j * 256 + w * 64) * 8);
    }
#pragma unroll
    for (int j = 0; j < BN / 32; ++j) {
      int ch = j * 256 + w * 64 + l, r = ch >> 3, c = ch & 7;
      gload16(Bp + (i64)r * ldb + kk + ((c ^ (r & 7)) << 3), Bd + (j * 256 + w * 64) * 8);
    }
  };
  const int nst = K >> 6;
  stage(0, 0);
  asm volatile("s_waitcnt vmcnt(0)" ::: "memory");
  __builtin_amdgcn_s_barrier();
  for (int s = 0; s < nst; ++s) {
    if (s + 1 < nst) stage((s + 1) << 6, (s + 1) & 1);  // prefetch overlaps MFMA below
    const u16* Ac = As + (s & 1) * (BM * 64);
    const u16* Bc = Bs + (s & 1) * (BN * 64);
#pragma unroll
    for (int kc = 0; kc < 2; ++kc) {
      const int sw = ((kc * 4 + quad) ^ (l15 & 7)) << 3;
      bf16x8 af[AM], bfr[AN];
#pragma unroll
      for (int i = 0; i < AM; ++i) af[i] = ldfrag(&Ac[(wm + i * 16 + l15) * 64 + sw]);
#pragma unroll
      for (int j = 0; j < AN; ++j) bfr[j] = ldfrag(&Bc[(wn + j * 16 + l15) * 64 + sw]);
#pragma unroll
      for (int i = 0; i < AM; ++i)
#pragma unroll
        for (int j = 0; j < AN; ++j) acc[i][j] = mfma16(af[i], bfr[j], acc[i][j]);
    }
    asm volatile("s_waitcnt vmcnt(0) lgkmcnt(0)" ::: "memory");
    __builtin_amdgcn_s_barrier();
  }
}

// ---------------- fused Q/K/V projection + Wc weight-GEMM, 128x128 tiles, flat grid 416 ----------------
__global__ __launch_bounds__(256) void qkv_gemm(const u16* __restrict__ cat,
                                                const u16* __restrict__ xkt,
                                                const u16* __restrict__ xvt,
                                                const u16* __restrict__ wqp,
                                                const u16* __restrict__ wkp,
                                                const u16* __restrict__ wvp,
                                                const u16* __restrict__ w1a,
                                                const u16* __restrict__ wmt,
                                                const float* __restrict__ bqp,
                                                const float* __restrict__ bkp,
                                                const float* __restrict__ bvp,
                                                u16* __restrict__ qh, u16* __restrict__ kh,
                                                u16* __restrict__ vt, u16* __restrict__ w1c) {
  __shared__ __align__(16) u16 As[2 * 128 * 64];
  __shared__ __align__(16) u16 Bs[2 * 128 * 64];
  const int flat = blockIdx.x;
  const int t = threadIdx.x, w = t >> 6, l = t & 63, quad = l >> 4, l15 = l & 15;
  const int wm = (w >> 1) * 64, wn = (w & 1) * 64;
  int op, b = 0, mx, ny;
  if (flat < 256) {        // Q (0..127) / K (128..255): M=2048, N=512 -> 16x4 per b
    op = flat >> 7;
    b = (flat >> 6) & 1;
    const int r = flat & 63;
    mx = r >> 2; ny = r & 3;
  } else if (flat < 384) {  // V: M=512, N=2048 -> 4x16 per b
    op = 2;
    const int r = flat - 256;
    b = r >> 6;
    const int rr = r & 63;
    mx = rr >> 4; ny = rr & 15;
  } else {                  // Wc: M=1024, N=512 -> 8x4
    op = 3;
    const int r = flat - 384;
    mx = r >> 2; ny = r & 3;
  }
  const u16 *A, *Bp;
  i64 lda, ldb;
  if (op < 2) {
    A = (op == 0 ? cat + DD : xkt);
    lda = (op == 0 ? D2 : DD);
    A += (i64)b * NN * lda + (i64)mx * 128 * lda;
    Bp = (op == 0 ? wqp : wkp) + (i64)ny * 128 * DD;
    ldb = DD;
  } else if (op == 2) {
    A = wvp + (i64)mx * 128 * DD; lda = DD;
    Bp = xvt + (i64)b * NN * DD + (i64)ny * 128 * DD; ldb = DD;
  } else {
    A = w1a + (i64)mx * 128 * DD; lda = DD;
    Bp = wmt + (i64)ny * 128 * DD; ldb = DD;
  }
  f32x4 acc[4][4] = {};
  gemm_core<4, 4>(A, lda, Bp, ldb, DD, As, Bs, acc);

  const int rowBase = mx * 128 + wm + quad * 4;
  const int colBase = ny * 128 + wn + l15;
  if (op < 2) {  // head scatter: col=h*64+dk -> [b][h][n][dk]; Q scaled by QSC
    const float* bias = (op == 0 ? bqp : bkp);
    const float sc = (op == 0 ? QSC : 1.f);
    u16* dst = (op == 0 ? qh : kh) + (i64)b * HH * NN * DKc;
#pragma unroll
    for (int j = 0; j < 4; ++j) {
      const int col = colBase + j * 16;
      const float cA = bias[col];
#pragma unroll
      for (int i = 0; i < 4; ++i)
#pragma unroll
        for (int r = 0; r < 4; ++r) {
          const int row = rowBase + i * 16 + r;
          dst[(i64)(col >> 6) * (NN * 64) + (i64)row * 64 + (col & 63)] =
              f2bf((acc[i][j][r] + cA) * sc);
        }
    }
  } else if (op == 2) {  // V: row bias, store [b][o'][m] (natural m)
    u16* dst = vt + (i64)b * HH * DKc * NN;
#pragma unroll
    for (int j = 0; j < 4; ++j) {
      const int col = colBase + j * 16;
#pragma unroll
      for (int i = 0; i < 4; ++i)
#pragma unroll
        for (int r = 0; r < 4; ++r) {
          const int row = rowBase + i * 16 + r;
          dst[(i64)row * NN + col] = f2bf(acc[i][j][r] + bvp[row]);
        }
    }
  } else {  // Wc plain store -> w1c[:, 0:512]
#pragma unroll
    for (int j = 0; j < 4; ++j) {
      const int col = colBase + j * 16;
#pragma unroll
      for (int i = 0; i < 4; ++i)
#pragma unroll
        for (int r = 0; r < 4; ++r) {
          const int row = rowBase + i * 16 + r;
          w1c[(i64)row * D2 + col] = f2bf(acc[i][j][r]);
        }
    }
  }
}

// ---------------- generic gemm_bt: C[m][n] = A[m][:]·B[n][:] (+epilogue) ----------------
struct GArgs {
  const u16* A; i64 lda, sAb;
  const u16* B; i64 ldb, sBb;
  void* C; i64 ldc, sCb;
  const float* p1; const float* p2;
  int K;
};

template <int MODE, int AM, int AN, int SWZ>
__global__ __launch_bounds__(256) void gemm_bt(GArgs g) {
  __shared__ __align__(16) u16 As[2 * AM * 32 * 64];
  __shared__ __align__(16) u16 Bs[2 * AN * 32 * 64];
  const int t = threadIdx.x, w = t >> 6, l = t & 63, quad = l >> 4, l15 = l & 15;
  const int wm = (w >> 1) * AM * 16, wn = (w & 1) * AN * 16;
  int bx = blockIdx.x, by = blockIdx.y, bz = blockIdx.z;
  if (SWZ == 1) {  // flat = bx + 8by + 256bz; pin same-by blocks to one XCD slot
    const int i = bx + (by << 3) + (bz << 8);
    const int slot = i & 7, jj = i >> 3;
    by = slot + ((jj & 3) << 3);
    const int j2 = jj >> 2;
    bx = j2 & 7;
    bz = j2 >> 3;
  }
  const u16* A = g.A + (i64)bz * g.sAb + (i64)bx * (AM * 32) * g.lda;
  const u16* Bp = g.B + (i64)bz * g.sBb + (i64)by * (AN * 32) * g.ldb;
  f32x4 acc[AM][AN] = {};
  gemm_core<AM, AN>(A, g.lda, Bp, g.ldb, g.K, As, Bs, acc);

  const int rowBase = bx * (AM * 32) + wm + quad * 4;
  const int colBase = by * (AN * 32) + wn + l15;
#pragma unroll
  for (int j = 0; j < AN; ++j) {
    const int col = colBase + j * 16;
    float cA = 0.f, cB = 0.f;
    if (MODE == 3) { cA = g.p1[col]; cB = g.p2[col]; }
#pragma unroll
    for (int i = 0; i < AM; ++i) {
#pragma unroll
      for (int r = 0; r < 4; ++r) {
        const int row = rowBase + i * 16 + r;
        float v = acc[i][j][r];
        if (MODE == 3) {  // BN+ReLU, bf16 out
          float x = v * cA + cB;
          ((u16*)g.C + (i64)bz * g.sCb)[(i64)row * g.ldc + col] = f2bf(x > 0.f ? x : 0.f);
        } else {  // MODE 4: fp32 out, row bias (W2 -> d_out)
          ((float*)g.C + (i64)bz * g.sCb)[(i64)row * g.ldc + col] = v + g.p1[row];
        }
      }
    }
  }
}

// ---------------- flash attention v15: full-KV per block, wave-split halves, fused combine ----------------
// S^T = mfma(A=K, B=Q); P^T stays in C-regs == valid B-operand for O^T = mfma(A=V^T, P^T).
// Each block: 128 q-rows x FULL 2048 kv. 8 waves = 4 q-groups x 2 kv-halves: wave (g,half)
// computes s-half `half` (kv rows half*32..+32 of each tile) for q-group g. Per-phase volume
// and barrier rhythm identical to the r2 kernel (16 phases, tile-pair staged per phase, dbuf);
// the s0/s1 halves one wave used to do back-to-back are simply owned by two waves.
// Tail: halves combine IN LDS (bf16 exchange, same precision as the old global partials), then
// the proven XOR-swizzled LDS transpose writes cat directly. No Opart/Lp, no combine kernel,
// no cross-block fences (r3's failure mode eliminated: all communication is intra-block).
__global__ __launch_bounds__(512) void flash_attn(const u16* __restrict__ Qh,
                                                  const u16* __restrict__ Kh,
                                                  const u16* __restrict__ Vt,
                                                  const u64* __restrict__ MW64,
                                                  u16* __restrict__ cat) {
  // 64KB: pair-slot S0 = {K(t) V(t) K(t+1) V(t+1)}, pair-slot S1 likewise
  __shared__ __align__(16) u16 smem[4 * 8192];
  u16* S0 = smem;
  u16* S1 = smem + 16384;
  const int t = threadIdx.x, w = t >> 6, l = t & 63, l31 = l & 31, lh = l >> 5;
  // flat decode pinning all blocks of head h to one XCD slot (RR dispatch, 256 blocks)
  const int flat = blockIdx.x;
  const int h = flat & 7;
  const int j = flat >> 3;             // [0,32)
  const int nt = j & 15, b = j >> 4;
  const int g = w & 3, half = w >> 2;  // q-group, kv-half of each tile
  const int nl = g * 32 + l31;         // local q row [0,128)
  const int n = nt * 128 + nl;         // global q row
  const u16* Qb = Qh + ((i64)(b * HH + h) * NN + nt * 128 + g * 32) * 64;
  const u16* Kb = Kh + (i64)(b * HH + h) * NN * 64;
  const u16* Vb = Vt + (i64)(b * HH + h) * 64 * NN;
  const u64* mwp = MW64 + (i64)(b * NN + n) * 32;
  const bf16x8 ONE = ones8();
  // Q fragments (B-operand): lane q=l31, k = kc*16 + lh*8 + j
  bf16x8 qf[4];
#pragma unroll
  for (int kc = 0; kc < 4; ++kc)
    __builtin_memcpy(&qf[kc], Qb + (i64)l31 * 64 + kc * 16 + lh * 8, 16);

  f32x16 oacc0 = {}, oacc1 = {}, lacc = {};
  const int hrow = half * 32 + l31;  // K LDS row this wave reads
  const int sw = l31 & 7;

  // 512 threads cover a full 64x64 K tile + V tile in ONE gload16 pair per thread
  auto stage = [&](u16* Kd, u16* Vd, int mt) {
    const int r = t >> 3, c = t & 7;
    gload16(Kb + (i64)(mt * 64 + r) * 64 + ((c ^ (r & 7)) << 3), Kd + t * 8);
    gload16(Vb + (i64)r * NN + mt * 64 + ((c ^ (r & 7)) << 3), Vd + t * 8);
  };
  auto stage_pair = [&](u16* S, int mt) {
    stage(S, S + 4096, mt);
    stage(S + 8192, S + 12288, mt + 1);
  };
  // this wave's kv-half of ONE tile (half the r2 per-tile work)
  auto compute_half = [&](const u16* Kc, const u16* Vc, int mt) {
    f32x16 s = {};
    __builtin_amdgcn_s_setprio(1);
#pragma unroll
    for (int kc = 0; kc < 4; ++kc) {
      bf16x8 k0 = ldfrag(&Kc[hrow * 64 + (((kc * 2 + lh) ^ sw) << 3)]);
      s = mfma32(k0, qf[kc], s);
    }
    __builtin_amdgcn_s_setprio(0);
    const u64 mrow = mwp[mt];
    u32 pw[8];
#pragma unroll
    for (int k = 0; k < 8; ++k) {
      const int kvb = ((2 * k) & 3) + 8 * ((2 * k) >> 2) + 4 * lh;
      const u32 m2 = (u32)(mrow >> (kvb + half * 32));
      const u32 mA = ((m2 & 1u) | ((m2 & 2u) << 15)) * 0xFFFFu;
      pw[k] = packbf(fexp2(s[2 * k]), fexp2(s[2 * k + 1])) & mA;
    }
    bf16x8 pf[2];
#pragma unroll
    for (int c = 0; c < 2; ++c) __builtin_memcpy(&pf[c], &pw[c * 4], 16);
    __builtin_amdgcn_s_setprio(1);
    lacc = mfma32(ONE, pf[0], lacc);
    lacc = mfma32(ONE, pf[1], lacc);
#pragma unroll
    for (int cc = 0; cc < 2; ++cc) {
      const int ch0 = 2 * (2 * half + cc), ch1 = ch0 + 1;
      const u16* r0 = &Vc[l31 * 64];
      const u16* r1 = &Vc[(32 + l31) * 64];
      bf16x8 v0 = ldfrag2(r0 + ((ch0 ^ sw) << 3) + lh * 4, r0 + ((ch1 ^ sw) << 3) + lh * 4);
      bf16x8 v1 = ldfrag2(r1 + ((ch0 ^ sw) << 3) + lh * 4, r1 + ((ch1 ^ sw) << 3) + lh * 4);
      oacc0 = mfma32(v0, pf[cc], oacc0);
      oacc1 = mfma32(v1, pf[cc], oacc1);
    }
    __builtin_amdgcn_s_setprio(0);
  };
  auto compute_pair = [&](const u16* S, int mt) {
    compute_half(S, S + 4096, mt);
    compute_half(S + 8192, S + 12288, mt + 1);
  };

  stage_pair(S0, 0);
  for (int ii = 0; ii < 8; ++ii) {   // 32 tiles = 16 pairs, dbuf at pair granularity
    const int m = 4 * ii;
    __syncthreads();                 // drains vmcnt -> S0 pair ready
    stage_pair(S1, m + 2);           // prefetch overlaps compute below
    compute_pair(S0, m);
    __syncthreads();                 // drains vmcnt -> S1 pair ready
    if (ii < 7) stage_pair(S0, m + 4);
    compute_pair(S1, m + 2);
  }

  // ---- fused combine, all intra-block ----
  __syncthreads();  // compute done; LDS free
  u32* ex = (u32*)smem;                         // [128 nl][32 dp] u32, XOR-swizzled (16KB)
  float* exl = (float*)((char*)smem + 16384);   // [128] f32 partial row-sums
  if (half == 1) {  // deposit partial O (bf16-packed, same precision as old global path) + l
#pragma unroll
    for (int e = 0; e < 8; ++e) {
      const int r0 = 2 * e, r1 = r0 + 1;
      const int dp = ((r0 & 3) + 8 * (r0 >> 2) + 4 * lh) >> 1;
      ex[nl * 32 + (dp ^ (nl & 31))] = packbf(oacc0[r0], oacc0[r1]);
      ex[nl * 32 + ((dp + 16) ^ (nl & 31))] = packbf(oacc1[r0], oacc1[r1]);
    }
    if (lh == 0) exl[nl] = lacc[0];
  }
  __syncthreads();
  u32* lt = (u32*)((char*)smem + 32768);        // transpose buffer (S1 region, 16KB)
  if (half == 0) {  // fold partner, normalize, swizzled transpose write
    const float lsum = lacc[0] + exl[nl];
    const float rl = __builtin_amdgcn_rcpf(lsum);
#pragma unroll
    for (int e = 0; e < 8; ++e) {
      const int r0 = 2 * e, r1 = r0 + 1;
      const int dp = ((r0 & 3) + 8 * (r0 >> 2) + 4 * lh) >> 1;
      const u32 va = ex[nl * 32 + (dp ^ (nl & 31))];
      const u32 vb = ex[nl * 32 + ((dp + 16) ^ (nl & 31))];
      lt[nl * 32 + (dp ^ (nl & 31))] =
          packbf((oacc0[r0] + bf2f32(va & 0xFFFFu)) * rl, (oacc0[r1] + bf2f32(va >> 16)) * rl);
      lt[nl * 32 + ((dp + 16) ^ (nl & 31))] =
          packbf((oacc1[r0] + bf2f32(vb & 0xFFFFu)) * rl, (oacc1[r1] + bf2f32(vb >> 16)) * rl);
    }
  }
  __syncthreads();
  // coalesced writeout: 128 n-rows x 32 u32 into cat[:, 0:512)
  u32* catw = (u32*)cat;
#pragma unroll
  for (int i = 0; i < 8; ++i) {
    const int idx = i * 512 + t;  // [0, 4096)
    const int nn = idx >> 5, dp = idx & 31;
    catw[((i64)b * NN + nt * 128 + nn) * (D2 / 2) + h * 32 + dp] = lt[nn * 32 + (dp ^ (nn & 31))];
  }
}

extern "C" void kernel_launch(void* const* d_in, const int* in_sizes, int n_in,
                              void* d_out, int out_size, void* d_ws, size_t ws_size,
                              hipStream_t stream) {
  (void)in_sizes; (void)n_in; (void)out_size; (void)ws_size;
  const float* iq    = (const float*)d_in[0];
  const float* kt    = (const float*)d_in[1];
  const float* vv    = (const float*)d_in[2];
  const int*   mask  = (const int*)d_in[3];
  const float* Wq    = (const float*)d_in[4];
  const float* bq    = (const float*)d_in[5];
  const float* Wk    = (const float*)d_in[6];
  const float* bk    = (const float*)d_in[7];
  const float* Wv    = (const float*)d_in[8];
  const float* bv    = (const float*)d_in[9];
  const float* Wm    = (const float*)d_in[10];
  const float* bm    = (const float*)d_in[11];
  const float* W1    = (const float*)d_in[12];
  const float* b1    = (const float*)d_in[13];
  const float* gamma_= (const float*)d_in[14];
  const float* beta_ = (const float*)d_in[15];
  const float* rmean = (const float*)d_in[16];
  const float* rvar  = (const float*)d_in[17];
  const float* W2    = (const float*)d_in[18];
  const float* b2    = (const float*)d_in[19];

  char* ws = (char*)d_ws;
  u16* cat = (u16*)(ws + OFF_CAT);
  u16* xkt = (u16*)(ws + OFF_XKT);
  u16* xvt = (u16*)(ws + OFF_XVT);
  u16* qh  = (u16*)(ws + OFF_QH);
  u16* kh  = (u16*)(ws + OFF_KH);
  u16* vt  = (u16*)(ws + OFF_VT);
  u16* ht  = (u16*)(ws + OFF_HT);
  u16* wqp = (u16*)(ws + OFF_WQP);
  u16* wkp = (u16*)(ws + OFF_WKP);
  u16* wvp = (u16*)(ws + OFF_WVP);
  u16* wmt = (u16*)(ws + OFF_WMT);
  u16* w1a = (u16*)(ws + OFF_W1A);
  u16* w1c = (u16*)(ws + OFF_W1C);
  u16* w2b = (u16*)(ws + OFF_W2B);
  float* bqp = (float*)(ws + OFF_BQP);
  float* bkp = (float*)(ws + OFF_BKP);
  float* bvp = (float*)(ws + OFF_BVP);
  float* bna = (float*)(ws + OFF_BNA);
  float* bnc = (float*)(ws + OFF_BNC);
  u32* mw = (u32*)(ws + OFF_MSK);

  // 1. prep (weights/BN/mask) + input transpose, one launch
  prep_all<<<8977, 256, 0, stream>>>(Wq, Wk, Wv, Wm, W1, W2, bq, bk, bv, bm, b1, gamma_, beta_,
                                     rmean, rvar, mask, iq, kt, vv, wqp, wkp, wvp, wmt, w1a, w1c,
                                     w2b, bqp, bkp, bvp, bna, bnc, mw, cat, xkt, xvt);
  // 2. fused Q/K/V projections + Wc, 128x128 tiles, flat grid (2-phase dbuf core)
  qkv_gemm<<<416, 256, 0, stream>>>(cat, xkt, xvt, wqp, wkp, wvp, w1a, wmt,
                                    bqp, bkp, bvp, qh, kh, vt, w1c);
  // 3. flash v15: 256 blocks, full-KV per block, wave-split halves, combine fused in LDS
  flash_attn<<<256, 512, 0, stream>>>(qh, kh, vt, (const u64*)mw, cat);
  // 4. W1' + BN + ReLU, batch-merged M=4096, 128x64 tiles (2-phase dbuf core)
  GArgs wa{cat, D2, 0, w1c, D2, 0, ht, D2, 0, bna, bnc, D2};
  gemm_bt<3, 4, 2, 0><<<dim3(32, 16, 1), 256, 0, stream>>>(wa);
  // 5. W2 -> d_out (fp32), B-tiles XCD-pinned via SWZ (2-phase dbuf core)
  GArgs w2a{w2b, D2, 0, ht, D2, (i64)NN * D2, d_out, NN, (i64)DD * NN, b2, nullptr, D2};
  gemm_bt<4, 2, 2, 1><<<dim3(8, 32, 2), 256, 0, stream>>>(w2a);
}